// Round 6
// baseline (252.519 us; speedup 1.0000x reference)
//
#include <hip/hip_runtime.h>

// Wave-synchronous fence: DS ops complete in order within a wave (ISA
// guarantee); this only stops the COMPILER from reordering/caching LDS.
#define WAVE_SYNC() do { asm volatile("" ::: "memory"); \
                         __builtin_amdgcn_wave_barrier(); \
                         asm volatile("" ::: "memory"); } while (0)

typedef _Float16 h2 __attribute__((ext_vector_type(2)));
typedef _Float16 h4 __attribute__((ext_vector_type(4)));
typedef _Float16 h8 __attribute__((ext_vector_type(8)));

__device__ __forceinline__ float fdot2(h2 a, h2 b, float c) {
#if defined(__has_builtin)
#if __has_builtin(__builtin_amdgcn_fdot2)
    return __builtin_amdgcn_fdot2(a, b, c, false);
#else
    return (float)a[0]*(float)b[0] + (float)a[1]*(float)b[1] + c;
#endif
#else
    return (float)a[0]*(float)b[0] + (float)a[1]*(float)b[1] + c;
#endif
}

__device__ __forceinline__ float dot8h(h8 a, h8 b, float c) {
    float s = c;
    #pragma unroll
    for (int i = 0; i < 4; ++i) {
        h2 x = {a[2*i], a[2*i+1]};
        h2 y = {b[2*i], b[2*i+1]};
        s = fdot2(x, y, s);
    }
    return s;
}

__device__ __forceinline__ float dot16h(h8 a0, h8 a1, h8 b0, h8 b1, float c) {
    return dot8h(a1, b1, dot8h(a0, b0, c));
}

__device__ __forceinline__ float ln_norm16(float z, float g, float bb) {
    float s = z, q = z * z;
    #pragma unroll
    for (int off = 8; off >= 1; off >>= 1) {
        s += __shfl_xor(s, off, 16);
        q += __shfl_xor(q, off, 16);
    }
    float mean = s * 0.0625f;
    float var  = q * 0.0625f - mean * mean;
    return (z - mean) * rsqrtf(var + 1e-5f) * g + bb;
}

__device__ __forceinline__ float gelu_exact(float a) {
    float xa = fabsf(a) * 0.70710678118654752f;
    float tt = 1.f / (1.f + 0.3275911f * xa);
    float poly = tt * (0.254829592f + tt * (-0.284496736f + tt * (1.421413741f
               + tt * (-1.453152027f + tt * 1.061405429f))));
    float erfv = 1.f - poly * __expf(-xa * xa);
    erfv = a >= 0.f ? erfv : -erfv;
    return 0.5f * a * (1.f + erfv);
}

// ========================= FUSED kernel v7 ===================================
// R5 analysis: wall = kernel + ~131us fixed overhead; kernel (88us) is >90%
// per-wave stall in phase A (one wave owned a whole sample's serial chain;
// only 8 waves/CU resident). v7: block = 128 thr = ONE sample, 2 waves SHARE
// phase A:
//   stage 0: 16 float4 loads/lane (was 32)      stage 1: 1 column/lane (was 2)
//   stage 2: 4 pool slots/lane (was 7)          stage 3: single pass
// Per-wave serial path ~halves; grid 2048 -> 8 blocks/CU x 2 waves =
// 16 waves/CU resident (2x R5). Cross-wave hazards (XSP aliases XR; pool;
// tok) guarded by __syncthreads (cheap at 2 waves).
// Phase B = R4's proven single-sample 128-thr transformer; its arena overlays
// the dead phase-A region; tok sits above both.
// LDS: max(phaseA 4448, phaseB 4696) + tok 80 = 4784 f32 = 19136 B
//   -> 8 blocks/CU (153 KB of 160). VGPR 128 via (128,2), no spill.

// ---- phase A layout (f32 idx) ----
#define F_XSTR 204         // XSP row stride (f32)
#define F_PL   4000        // pool region (f32 idx; XR occupies [0,4000))
#define TOKF   4704        // tok: 80 f32 (byte 18816, above phase-B arena)
#define FUSED_TOTF 4784    // 19136 B total

// ---- phase B arena (same offsets as R4 transformer, single strip) ----
#define WQKVH 0          // halfs: 192 rows, stride 24
#define WOUTH 4608       // 16 rows, stride 72
#define WM1H  5760       // 32 rows, stride 24
#define WM2H  6528       // 16 rows, stride 40
#define BQKVF 3584       // f32 idx
#define BOUTF 3776
#define BM1F  3792
#define BM2F  3824
#define LN1GF 3840
#define LN1BF 3856
#define LN2GF 3872
#define LN2BF 3888
#define SCR0  7808       // half idx (scratch strip, 1584 halfs -> ends 9392)
#define SH1H  0
#define SQKVH 144
#define SMHSH 1344

extern "C" __global__ __launch_bounds__(128, 2)
void eegnet_fused(
    const float* __restrict__ x,
    const float* __restrict__ conv_t_w, const float* __restrict__ conv_t_b,
    const float* __restrict__ bn1_g, const float* __restrict__ bn1_b,
    const float* __restrict__ bn1_m, const float* __restrict__ bn1_v,
    const float* __restrict__ conv_s_w, const float* __restrict__ conv_s_b,
    const float* __restrict__ bn2_g, const float* __restrict__ bn2_b,
    const float* __restrict__ bn2_m, const float* __restrict__ bn2_v,
    const float* __restrict__ proj_w, const float* __restrict__ proj_b,
    const float* __restrict__ cls_token, const float* __restrict__ pe,
    const float* __restrict__ qkv_w, const float* __restrict__ qkv_b,
    const float* __restrict__ out_w, const float* __restrict__ out_b,
    const float* __restrict__ ln1_g, const float* __restrict__ ln1_b,
    const float* __restrict__ ln2_g, const float* __restrict__ ln2_b,
    const float* __restrict__ mlp_w1, const float* __restrict__ mlp_b1,
    const float* __restrict__ mlp_w2, const float* __restrict__ mlp_b2,
    const float* __restrict__ head_ln_g, const float* __restrict__ head_ln_b,
    const float* __restrict__ head_w, const float* __restrict__ head_b,
    float* __restrict__ out)
{
    __shared__ __align__(16) float sm[FUSED_TOTF];
    _Float16* smh = reinterpret_cast<_Float16*>(sm);
    _Float16* xr  = reinterpret_cast<_Float16*>(sm);

    const int tid = threadIdx.x;
    const int b   = blockIdx.x;        // one sample per block

    // ======================= PHASE A: conv frontend ==========================
    // ---- stage 0: x -> XR f16 ring (128 lanes, coalesced float4) ----
    {
        const float4* xb4 = reinterpret_cast<const float4*>(x + (size_t)b * 8000);
        #pragma unroll
        for (int k = 0; k < 16; ++k) {
            int g = min(tid + k * 128, 1999);     // tail lanes dup (same value)
            float4 v = xb4[g];
            h4 hv = {(_Float16)v.x, (_Float16)v.y, (_Float16)v.z, (_Float16)v.w};
            *reinterpret_cast<h4*>(&xr[4 * g]) = hv;
        }
    }
    __syncthreads();   // XR complete (cross-wave)

    // ---- stage 1: spatial conv; one time-column per lane ----
    float acc[16];
    #pragma unroll
    for (int o = 0; o < 16; ++o) acc[o] = 0.f;
    {
        const int t = min(tid, 124);
        #pragma unroll 8
        for (int c = 0; c < 64; ++c) {
            float xv = (float)xr[c * 125 + t];
            #pragma unroll
            for (int o = 0; o < 16; ++o)
                acc[o] += conv_s_w[o * 64 + c] * xv;   // wave-uniform -> s_load
        }
    }
    __syncthreads();   // ALL XR reads retired before aliased XSP writes

    // ---- write XSP (aliases XR): zero pads + conv rows ----
    for (int i = tid; i < 16 * 79; i += 128) {
        int row = i / 79, k = i - row * 79;
        int off = (k < 32) ? k : (k + 125);
        sm[row * F_XSTR + off] = 0.f;
    }
    if (tid < 125) {
        #pragma unroll
        for (int o = 0; o < 16; ++o)
            sm[o * F_XSTR + 32 + tid] = acc[o];
    }
    __syncthreads();   // XSP ready (cross-wave)

    // ---- fused BN constants + temporal taps ----
    const int oo = tid & 15, qg8 = tid >> 4, gg = oo >> 1;
    {
        float sa, cc;
        {
            float s1 = bn1_g[gg] * rsqrtf(bn1_v[gg] + 1e-5f);
            float b1 = (conv_t_b[gg] - bn1_m[gg]) * s1 + bn1_b[gg];
            float s2 = bn2_g[oo] * rsqrtf(bn2_v[oo] + 1e-5f);
            float ssum = 0.f;
            const float4* csw = reinterpret_cast<const float4*>(conv_s_w + oo * 64);
            #pragma unroll
            for (int i = 0; i < 16; ++i) {
                float4 v = csw[i];
                ssum += v.x + v.y + v.z + v.w;
            }
            sa = s1 * s2;
            cc = (b1 * ssum + conv_s_b[oo] - bn2_m[oo]) * s2 + bn2_b[oo];
        }
        float wt[63];
        #pragma unroll
        for (int k = 0; k < 63; ++k) wt[k] = conv_t_w[gg * 63 + k];

        // ---- stage 2: temporal conv + BN + ELU + avg-pool (4 slots/lane) ----
        #pragma unroll 2
        for (int jj = 0; jj < 4; ++jj) {
            int j  = qg8 * 4 + jj;          // 0..31; 25..31 clamped dups
            int jc = min(j, 24);
            int base = oo * F_XSTR + 5 * jc + 1;
            float acc5[5] = {0.f, 0.f, 0.f, 0.f, 0.f};
            #pragma unroll
            for (int m = 0; m < 67; ++m) {
                float xv = sm[base + m];
                #pragma unroll
                for (int u = 0; u < 5; ++u)
                    if (u <= m && m - u <= 62) acc5[u] += wt[m - u] * xv;
            }
            float psum = 0.f;
            #pragma unroll
            for (int u = 0; u < 5; ++u) {
                float v = acc5[u] * sa + cc;
                psum += (v > 0.f) ? v : (__expf(v) - 1.f);
            }
            if (j == jc) sm[F_PL + oo * 28 + j] = psum * 0.2f;
        }
    }
    __syncthreads();   // pool ready (cross-wave)

    // ---- stage 3: token projection -> LDS tok ----
    if (tid < 80) {
        int p = tid >> 4, dd = tid & 15;
        float acc3 = proj_b[dd];
        const float4* wp = reinterpret_cast<const float4*>(proj_w + dd * 80);
        #pragma unroll
        for (int i = 0; i < 20; ++i) {
            float4 w4 = wp[i];
            acc3 += w4.x * sm[F_PL + ((4*i+0)/5) * 28 + p * 5 + ((4*i+0)%5)];
            acc3 += w4.y * sm[F_PL + ((4*i+1)/5) * 28 + p * 5 + ((4*i+1)%5)];
            acc3 += w4.z * sm[F_PL + ((4*i+2)/5) * 28 + p * 5 + ((4*i+2)%5)];
            acc3 += w4.w * sm[F_PL + ((4*i+3)/5) * 28 + p * 5 + ((4*i+3)%5)];
        }
        sm[TOKF + p * 16 + dd] = acc3;
    }
    __syncthreads();   // tok ready; phase-A arena dead below here

    // ======================= PHASE B: transformer + head =====================
    const int d16 = tid & 15, qg = tid >> 4;
    const int t6c = min(qg, 5);
    const int wav = tid >> 6, al = tid & 63;
    const int sb  = SCR0;
    const int sA  = blockIdx.x;

    float zA;
    {
        float peV = pe[t6c * 16 + d16];
        if (t6c == 0) zA = cls_token[d16] + peV;
        else          zA = sm[TOKF + (t6c - 1) * 16 + d16] + peV;
    }

    #pragma unroll 1
    for (int li = 0; li < 6; ++li) {
        __syncthreads();

        {
            const float4* s1 = reinterpret_cast<const float4*>(qkv_w + li * 3072);
            #pragma unroll
            for (int it = 0; it < 6; ++it) {
                int i = tid + it * 128;           // 768 float4
                float4 v = s1[i];
                int j = i >> 2, k = (i & 3) << 2;
                h4 hv = {(_Float16)v.x, (_Float16)v.y, (_Float16)v.z, (_Float16)v.w};
                *reinterpret_cast<h4*>(&smh[WQKVH + j * 24 + k]) = hv;
            }
            const float4* s2 = reinterpret_cast<const float4*>(out_w + li * 1024);
            #pragma unroll
            for (int it = 0; it < 2; ++it) {
                int i = tid + it * 128;           // 256 float4
                float4 v = s2[i];
                int j = i >> 4, k = (i & 15) << 2;
                h4 hv = {(_Float16)v.x, (_Float16)v.y, (_Float16)v.z, (_Float16)v.w};
                *reinterpret_cast<h4*>(&smh[WOUTH + j * 72 + k]) = hv;
            }
            {
                float4 v = reinterpret_cast<const float4*>(mlp_w1 + li * 512)[tid];
                int j = tid >> 2, k = (tid & 3) << 2;
                h4 hv = {(_Float16)v.x, (_Float16)v.y, (_Float16)v.z, (_Float16)v.w};
                *reinterpret_cast<h4*>(&smh[WM1H + j * 24 + k]) = hv;
            }
            {
                float4 v = reinterpret_cast<const float4*>(mlp_w2 + li * 512)[tid];
                int j = tid >> 3, k = (tid & 7) << 2;
                h4 hv = {(_Float16)v.x, (_Float16)v.y, (_Float16)v.z, (_Float16)v.w};
                *reinterpret_cast<h4*>(&smh[WM2H + j * 40 + k]) = hv;
            }
            #pragma unroll
            for (int p = 0; p < 2; ++p) {
                int i = tid + p * 128;            // 256 bias slots
                if (i < 192)       sm[BQKVF + i]       = qkv_b[li * 192 + i];
                else if (i < 208)  sm[BOUTF + i - 192] = out_b[li * 16 + i - 192];
                else if (i < 240)  sm[BM1F + i - 208]  = mlp_b1[li * 32 + i - 208];
                else               sm[BM2F + i - 240]  = mlp_b2[li * 16 + i - 240];
            }
            if (tid >= 64 && tid < 80)        sm[LN1GF + tid - 64]  = ln1_g[li * 16 + tid - 64];
            else if (tid >= 80 && tid < 96)   sm[LN1BF + tid - 80]  = ln1_b[li * 16 + tid - 80];
            else if (tid >= 96 && tid < 112)  sm[LN2GF + tid - 96]  = ln2_g[li * 16 + tid - 96];
            else if (tid >= 112 && tid < 128) sm[LN2BF + tid - 112] = ln2_b[li * 16 + tid - 112];
        }
        __syncthreads();

        {
            float g = sm[LN1GF + d16], bb = sm[LN1BF + d16];
            smh[sb + SH1H + t6c * 24 + d16] = (_Float16)ln_norm16(zA, g, bb);
        }
        WAVE_SYNC();

        h8 hA0 = *reinterpret_cast<const h8*>(&smh[sb + SH1H + t6c * 24]);
        h8 hA1 = *reinterpret_cast<const h8*>(&smh[sb + SH1H + t6c * 24 + 8]);

        #pragma unroll 2
        for (int r = 0; r < 12; ++r) {
            int j = d16 + 16 * r;
            h8 w0 = *reinterpret_cast<const h8*>(&smh[WQKVH + j * 24]);
            h8 w1 = *reinterpret_cast<const h8*>(&smh[WQKVH + j * 24 + 8]);
            float bb = sm[BQKVF + j];
            smh[sb + SQKVH + t6c * 200 + j] = (_Float16)dot16h(hA0, hA1, w0, w1, bb);
        }
        __syncthreads();

        {
            bool act = (wav == 0) ? (al < 32) : (al < 16);
            if (act) {
                int h  = al & 7;
                int qs = (wav == 0) ? (al >> 3) : 4 + (al >> 3);
                const int qoff = sb + SQKVH + qs * 200 + h * 8;
                h8 qA = *reinterpret_cast<const h8*>(&smh[qoff]);
                float scA[6];
                #pragma unroll
                for (int t = 0; t < 6; ++t) {
                    h8 kA = *reinterpret_cast<const h8*>(&smh[sb + SQKVH + t * 200 + 64 + h * 8]);
                    scA[t] = dot8h(qA, kA, 0.f) * 0.35355339059327373f;
                }
                float mxA = scA[0];
                #pragma unroll
                for (int t = 1; t < 6; ++t) mxA = fmaxf(mxA, scA[t]);
                float suA = 0.f;
                #pragma unroll
                for (int t = 0; t < 6; ++t) { scA[t] = __expf(scA[t] - mxA); suA += scA[t]; }
                float ivA = 1.f / suA;
                h2 oA[4];
                #pragma unroll
                for (int k2 = 0; k2 < 4; ++k2) oA[k2] = h2{0, 0};
                #pragma unroll
                for (int t = 0; t < 6; ++t) {
                    h8 vA = *reinterpret_cast<const h8*>(&smh[sb + SQKVH + t * 200 + 128 + h * 8]);
                    _Float16 aa = (_Float16)(scA[t] * ivA);
                    h2 av = {aa, aa};
                    #pragma unroll
                    for (int k2 = 0; k2 < 4; ++k2) {
                        h2 va = {vA[2*k2], vA[2*k2+1]};
                        oA[k2] += av * va;
                    }
                }
                h8 stA;
                #pragma unroll
                for (int k2 = 0; k2 < 4; ++k2) {
                    stA[2*k2] = oA[k2][0]; stA[2*k2+1] = oA[k2][1];
                }
                *reinterpret_cast<h8*>(&smh[qoff]) = stA;
            }
        }
        WAVE_SYNC();

        {
            float aA = sm[BOUTF + d16];
            #pragma unroll
            for (int i = 0; i < 8; ++i) {
                h8 wv = *reinterpret_cast<const h8*>(&smh[WOUTH + d16 * 72 + 8 * i]);
                h8 va = *reinterpret_cast<const h8*>(&smh[sb + SQKVH + t6c * 200 + 8 * i]);
                aA = dot8h(va, wv, aA);
            }
            zA += aA;
        }

        {
            float g = sm[LN2GF + d16], bb = sm[LN2BF + d16];
            smh[sb + SH1H + t6c * 24 + d16] = (_Float16)ln_norm16(zA, g, bb);
        }
        WAVE_SYNC();
        hA0 = *reinterpret_cast<const h8*>(&smh[sb + SH1H + t6c * 24]);
        hA1 = *reinterpret_cast<const h8*>(&smh[sb + SH1H + t6c * 24 + 8]);

        #pragma unroll
        for (int r = 0; r < 2; ++r) {
            int uu = d16 + 16 * r;
            h8 w0 = *reinterpret_cast<const h8*>(&smh[WM1H + uu * 24]);
            h8 w1 = *reinterpret_cast<const h8*>(&smh[WM1H + uu * 24 + 8]);
            float bb = sm[BM1F + uu];
            float aA = dot16h(hA0, hA1, w0, w1, bb);
            smh[sb + SMHSH + t6c * 40 + uu] = (_Float16)gelu_exact(aA);
        }
        WAVE_SYNC();

        {
            float aA = sm[BM2F + d16];
            #pragma unroll
            for (int i = 0; i < 4; ++i) {
                h8 wv = *reinterpret_cast<const h8*>(&smh[WM2H + d16 * 40 + 8 * i]);
                h8 va = *reinterpret_cast<const h8*>(&smh[sb + SMHSH + t6c * 40 + 8 * i]);
                aA = dot8h(va, wv, aA);
            }
            zA += aA;
        }
    }

    if (tid < 16) {
        float g = head_ln_g[d16], bb = head_ln_b[d16];
        float w0 = head_w[d16], w1 = head_w[16 + d16];
        float cvA = ln_norm16(zA, g, bb);
        float pA0 = cvA * w0, pA1 = cvA * w1;
        #pragma unroll
        for (int off = 8; off >= 1; off >>= 1) {
            pA0 += __shfl_xor(pA0, off, 16);
            pA1 += __shfl_xor(pA1, off, 16);
        }
        if (tid == 0) {
            float l0 = pA0 + head_b[0], l1 = pA1 + head_b[1];
            float mx = fmaxf(l0, l1);
            float e0 = __expf(l0 - mx), e1 = __expf(l1 - mx);
            float inv = 1.f / (e0 + e1);
            out[sA * 2 + 0] = e0 * inv;
            out[sA * 2 + 1] = e1 * inv;
        }
    }
}

extern "C" void kernel_launch(void* const* d_in, const int* in_sizes, int n_in,
                              void* d_out, int out_size, void* d_ws, size_t ws_size,
                              hipStream_t stream) {
    (void)n_in; (void)ws_size; (void)out_size; (void)d_ws;
    const float* a0  = (const float*)d_in[0];   // x
    const float* a1  = (const float*)d_in[1];   // conv_t_w
    const float* a2  = (const float*)d_in[2];   // conv_t_b
    const float* a3  = (const float*)d_in[3];   // bn1_g
    const float* a4  = (const float*)d_in[4];   // bn1_b
    const float* a5  = (const float*)d_in[5];   // bn1_m
    const float* a6  = (const float*)d_in[6];   // bn1_v
    const float* a7  = (const float*)d_in[7];   // conv_s_w
    const float* a8  = (const float*)d_in[8];   // conv_s_b
    const float* a9  = (const float*)d_in[9];   // bn2_g
    const float* a10 = (const float*)d_in[10];  // bn2_b
    const float* a11 = (const float*)d_in[11];  // bn2_m
    const float* a12 = (const float*)d_in[12];  // bn2_v
    const float* a13 = (const float*)d_in[13];  // proj_w
    const float* a14 = (const float*)d_in[14];  // proj_b
    const float* a15 = (const float*)d_in[15];  // cls_token
    const float* a16 = (const float*)d_in[16];  // pe
    const float* a17 = (const float*)d_in[17];  // qkv_w
    const float* a18 = (const float*)d_in[18];  // qkv_b
    const float* a19 = (const float*)d_in[19];  // out_w
    const float* a20 = (const float*)d_in[20];  // out_b
    const float* a21 = (const float*)d_in[21];  // ln1_g
    const float* a22 = (const float*)d_in[22];  // ln1_b
    const float* a23 = (const float*)d_in[23];  // ln2_g
    const float* a24 = (const float*)d_in[24];  // ln2_b
    const float* a25 = (const float*)d_in[25];  // mlp_w1
    const float* a26 = (const float*)d_in[26];  // mlp_b1
    const float* a27 = (const float*)d_in[27];  // mlp_w2
    const float* a28 = (const float*)d_in[28];  // mlp_b2
    const float* a29 = (const float*)d_in[29];  // head_ln_g
    const float* a30 = (const float*)d_in[30];  // head_ln_b
    const float* a31 = (const float*)d_in[31];  // head_w
    const float* a32 = (const float*)d_in[32];  // head_b

    int Bn = in_sizes[0] / (64 * 125);          // 2048

    eegnet_fused<<<Bn, 128, 0, stream>>>(
        a0, a1, a2, a3, a4, a5, a6, a7, a8, a9, a10, a11, a12,
        a13, a14, a15, a16, a17, a18, a19, a20, a21, a22, a23, a24,
        a25, a26, a27, a28, a29, a30, a31, a32, (float*)d_out);
}